// Round 8
// baseline (784.394 us; speedup 1.0000x reference)
//
#include <hip/hip_runtime.h>

// Problem constants (B=8, C=64, W=496, H=432)
#define WH      214272            // 496*432 pixels per (b,c) plane
#define GPB     53568             // WH/4 float4 groups per plane (mult of 64)
#define TOTAL4  (512*GPB)         // all float4 elements = 27,426,816
#define CHUNKS  (TOTAL4/64)       // 64-float4 (1 KB/wave) chunks = 428544
#define CPP     (GPB/64)          // chunks per plane = 837
#define HALF_CH (CHUNKS/2)        // 214272 chunks = planes [0,256) | [256,512), 219 MB each

#define SBLK    1024              // blocks per half-launch
#define SW      (SBLK*4)          // 4096 waves
#define SPER    ((HALF_CH + SW - 1)/SW)   // 53 chunks per wave

#define NREP    16                // accumulator replicas (atomic de-contention, R4-proven)
// ws layout (floats): gsum[NREP][64] @0, gsq[NREP][64] @1024, gn[8][8] ints @2048
#define WS_FLOATS (NREP*64*2 + 64)

typedef float floatx4 __attribute__((ext_vector_type(4)));

// ---------------- K1: per-channel sum/sumsq + per-batch mask count (one half) -------
// DETERMINISTIC PHASED L3 REUSE (the round's single variable): x is processed in two
// 219MB halves, each < 256MB L3. Schedule: statsA, statsB, scaleB, scaleA.
//  - statsB's plain-load allocations leave ALL of B resident -> scaleB reads are L3
//    hits by construction (no LRU race: B fits entirely).
//  - scaleA's plain loads re-allocate A at iteration end -> next iteration's statsA
//    hits A. Steady-state HBM/iter ~880MB (vs 1314 zero-reuse).
// Inner loop: R4-proven 8-deep pipeline, 4 independent (s,q) pairs, 16-way replicas.
// Mask: occ zeroes all channels of a pixel together -> channel 0 alone decides.
__global__ __launch_bounds__(256, 4) void k_stats(const floatx4* __restrict__ x4,
                                                  float* __restrict__ gsum,
                                                  float* __restrict__ gsq,
                                                  int* __restrict__ gn,
                                                  int base) {
    const int lane = threadIdx.x & 63;
    const int gw   = blockIdx.x * 4 + (threadIdx.x >> 6);   // wave id within launch
    const int rep  = gw & (NREP - 1);
    int c0 = base + gw * SPER;
    const int c1 = min(c0 + SPER, base + HALF_CH);

    while (c0 < c1) {
        const int plane = (int)((unsigned)c0 / CPP);        // wave-uniform
        const int run   = min(c1, (plane + 1) * CPP);       // end of this plane-run
        const bool isC0 = (plane & 63) == 0;

        float s0 = 0.f, s1 = 0.f, s2 = 0.f, s3 = 0.f;
        float q0 = 0.f, q1 = 0.f, q2 = 0.f, q3 = 0.f;
        int cnt = 0;
        const floatx4* p = x4 + (size_t)c0 * 64 + lane;
        const int n = run - c0;
        int k = 0;
        for (; k + 8 <= n; k += 8) {
            const floatx4 v0 = p[(size_t)(k + 0) * 64];
            const floatx4 v1 = p[(size_t)(k + 1) * 64];
            const floatx4 v2 = p[(size_t)(k + 2) * 64];
            const floatx4 v3 = p[(size_t)(k + 3) * 64];
            const floatx4 v4 = p[(size_t)(k + 4) * 64];
            const floatx4 v5 = p[(size_t)(k + 5) * 64];
            const floatx4 v6 = p[(size_t)(k + 6) * 64];
            const floatx4 v7 = p[(size_t)(k + 7) * 64];
            s0 += (v0.x + v0.y) + (v0.z + v0.w);
            s1 += (v1.x + v1.y) + (v1.z + v1.w);
            s2 += (v2.x + v2.y) + (v2.z + v2.w);
            s3 += (v3.x + v3.y) + (v3.z + v3.w);
            q0 = fmaf(v0.w, v0.w, fmaf(v0.z, v0.z, fmaf(v0.y, v0.y, fmaf(v0.x, v0.x, q0))));
            q1 = fmaf(v1.w, v1.w, fmaf(v1.z, v1.z, fmaf(v1.y, v1.y, fmaf(v1.x, v1.x, q1))));
            q2 = fmaf(v2.w, v2.w, fmaf(v2.z, v2.z, fmaf(v2.y, v2.y, fmaf(v2.x, v2.x, q2))));
            q3 = fmaf(v3.w, v3.w, fmaf(v3.z, v3.z, fmaf(v3.y, v3.y, fmaf(v3.x, v3.x, q3))));
            s0 += (v4.x + v4.y) + (v4.z + v4.w);
            s1 += (v5.x + v5.y) + (v5.z + v5.w);
            s2 += (v6.x + v6.y) + (v6.z + v6.w);
            s3 += (v7.x + v7.y) + (v7.z + v7.w);
            q0 = fmaf(v4.w, v4.w, fmaf(v4.z, v4.z, fmaf(v4.y, v4.y, fmaf(v4.x, v4.x, q0))));
            q1 = fmaf(v5.w, v5.w, fmaf(v5.z, v5.z, fmaf(v5.y, v5.y, fmaf(v5.x, v5.x, q1))));
            q2 = fmaf(v6.w, v6.w, fmaf(v6.z, v6.z, fmaf(v6.y, v6.y, fmaf(v6.x, v6.x, q2))));
            q3 = fmaf(v7.w, v7.w, fmaf(v7.z, v7.z, fmaf(v7.y, v7.y, fmaf(v7.x, v7.x, q3))));
            if (isC0) {
                cnt += (v0.x != 0.f) + (v0.y != 0.f) + (v0.z != 0.f) + (v0.w != 0.f);
                cnt += (v1.x != 0.f) + (v1.y != 0.f) + (v1.z != 0.f) + (v1.w != 0.f);
                cnt += (v2.x != 0.f) + (v2.y != 0.f) + (v2.z != 0.f) + (v2.w != 0.f);
                cnt += (v3.x != 0.f) + (v3.y != 0.f) + (v3.z != 0.f) + (v3.w != 0.f);
                cnt += (v4.x != 0.f) + (v4.y != 0.f) + (v4.z != 0.f) + (v4.w != 0.f);
                cnt += (v5.x != 0.f) + (v5.y != 0.f) + (v5.z != 0.f) + (v5.w != 0.f);
                cnt += (v6.x != 0.f) + (v6.y != 0.f) + (v6.z != 0.f) + (v6.w != 0.f);
                cnt += (v7.x != 0.f) + (v7.y != 0.f) + (v7.z != 0.f) + (v7.w != 0.f);
            }
        }
        for (; k < n; ++k) {
            const floatx4 v = p[(size_t)k * 64];
            s0 += (v.x + v.y) + (v.z + v.w);
            q0 = fmaf(v.w, v.w, fmaf(v.z, v.z, fmaf(v.y, v.y, fmaf(v.x, v.x, q0))));
            if (isC0) cnt += (v.x != 0.f) + (v.y != 0.f) + (v.z != 0.f) + (v.w != 0.f);
        }
        float ss = (s0 + s1) + (s2 + s3);
        float qq = (q0 + q1) + (q2 + q3);
#pragma unroll
        for (int m = 1; m < 64; m <<= 1) {
            ss += __shfl_xor(ss, m, 64);
            qq += __shfl_xor(qq, m, 64);
        }
        if (isC0) {
#pragma unroll
            for (int m = 1; m < 64; m <<= 1) cnt += __shfl_xor(cnt, m, 64);
        }
        if (lane == 0) {
            atomicAdd(&gsum[rep * 64 + (plane & 63)], ss);
            atomicAdd(&gsq[rep * 64 + (plane & 63)], qq);
            if (isC0) atomicAdd(&gn[(rep & 7) * 8 + (plane >> 6)], cnt);
        }
        c0 = run;
    }
}

// ---------------- K2: finalize (prologue) + out = x * inv[c] over one half ----------
// PLAIN loads (scaleB: all-L3-hit by construction; scaleA: re-allocates A for next
// iteration's statsA). NT stores (R3: plain stores regress). Reverse walk: free
// upside on whatever leftover recency exists.
__global__ __launch_bounds__(256, 8) void k_scale(const floatx4* __restrict__ x4,
                                                  floatx4* __restrict__ out4,
                                                  const float* __restrict__ gsum,
                                                  const float* __restrict__ gsq,
                                                  const int* __restrict__ gn,
                                                  int base) {
    __shared__ float sinv[64];
    const int tid = threadIdx.x;
    if (tid < 64) {
        const int c = tid;
        const float* x = (const float*)x4;
        float total = 0.f, S2 = 0.f;
#pragma unroll
        for (int r = 0; r < NREP; ++r) {
            total += gsum[r * 64 + c];
            S2    += gsq[r * 64 + c];
        }
        int nb[8];
        int N = 0;
#pragma unroll
        for (int b = 0; b < 8; ++b) {
            int v = 0;
#pragma unroll
            for (int r = 0; r < 8; ++r) v += gn[r * 8 + b];
            nb[b] = v;
            N = max(N, v);
        }
#pragma unroll
        for (int b = 0; b < 8; ++b) {
            const float pad = (float)(N - nb[b]);
            const float x00 = x[(size_t)(b * 64 + c) * WH];
            total = fmaf(pad, x00, total);
            S2    = fmaf(pad, x00 * x00, S2);
        }
        const float count = (float)(8 * N);
        const float mean  = total / count;
        const float var   = S2 / count - mean * mean;
        sinv[c] = 1.0f / sqrtf(var + 0.001f);
    }
    __syncthreads();

    const int lane = tid & 63;
    const int gw   = blockIdx.x * 4 + (tid >> 6);   // wave id within launch
    const int c0   = base + gw * SPER;
    const int c1   = min(c0 + SPER, base + HALF_CH);
#pragma unroll 4
    for (int ch = c1 - 1; ch >= c0; --ch) {
        const int plane = (int)((unsigned)ch / CPP);      // wave-uniform
        const float inv = sinv[plane & 63];
        const size_t i = (size_t)ch * 64 + lane;
        floatx4 v = x4[i];
        v.x *= inv; v.y *= inv; v.z *= inv; v.w *= inv;
        __builtin_nontemporal_store(v, &out4[i]);
    }
}

extern "C" void kernel_launch(void* const* d_in, const int* in_sizes, int n_in,
                              void* d_out, int out_size, void* d_ws, size_t ws_size,
                              hipStream_t stream) {
    const float* x  = (const float*)d_in[0];
    float* out      = (float*)d_out;
    float* wsf      = (float*)d_ws;
    float* gsum     = wsf;                        // [NREP][64]
    float* gsq      = wsf + NREP * 64;            // [NREP][64]
    int*   gn       = (int*)(wsf + NREP * 128);   // [8][8]

    (void)hipMemsetAsync(d_ws, 0, WS_FLOATS * sizeof(float), stream);

    // Phased schedule: statsA, statsB, scaleB (B fully L3-resident), scaleA
    // (re-allocates A for next iteration's statsA). Kernel boundaries = global syncs.
    k_stats<<<SBLK, 256, 0, stream>>>((const floatx4*)x, gsum, gsq, gn, 0);
    k_stats<<<SBLK, 256, 0, stream>>>((const floatx4*)x, gsum, gsq, gn, HALF_CH);
    k_scale<<<SBLK, 256, 0, stream>>>((const floatx4*)x, (floatx4*)out,
                                      gsum, gsq, gn, HALF_CH);
    k_scale<<<SBLK, 256, 0, stream>>>((const floatx4*)x, (floatx4*)out,
                                      gsum, gsq, gn, 0);
}